// Round 4
// baseline (889.854 us; speedup 1.0000x reference)
//
#include <hip/hip_runtime.h>

typedef unsigned short u16;
typedef unsigned int u32;
typedef u16 u16x8 __attribute__((ext_vector_type(8)));
typedef __bf16 bf16x8 __attribute__((ext_vector_type(8)));
typedef float f32x4 __attribute__((ext_vector_type(4)));

#define TOKENS 4096
#define DMODEL 4096
#define QKVN 6144
#define NHEAD 32
#define NKV 8
#define DHEAD 128
#define SEQ 2048

__device__ inline u16 f2bf(float f) {
    unsigned int u = __float_as_uint(f);
    u += 0x7fffu + ((u >> 16) & 1u);
    return (u16)(u >> 16);
}
__device__ inline float bf2f(u16 h) {
    return __uint_as_float(((unsigned int)h) << 16);
}
__device__ inline u32 pk_bf2(float a, float b) {
    return (u32)f2bf(a) | ((u32)f2bf(b) << 16);
}
__device__ inline f32x4 mfma16(bf16x8 a, bf16x8 b, f32x4 c) {
    return __builtin_amdgcn_mfma_f32_16x16x32_bf16(a, b, c, 0, 0, 0);
}
__device__ __forceinline__ void gload16(const u16* g, u16* l) {
    __builtin_amdgcn_global_load_lds((const __attribute__((address_space(1))) u32*)g,
                                     (__attribute__((address_space(3))) u32*)l, 16, 0, 0);
}

// ---------------- fp32 -> bf16 convert ----------------
__global__ __launch_bounds__(256) void f2bf_kernel(const float* __restrict__ in,
                                                   u16* __restrict__ out, int n) {
    int i = (blockIdx.x * 256 + threadIdx.x) * 4;
    if (i >= n) return;
    float4 v = *(const float4*)(in + i);
    u16 o0 = f2bf(v.x), o1 = f2bf(v.y), o2 = f2bf(v.z), o3 = f2bf(v.w);
    u16* p = out + i;
    p[0] = o0; p[1] = o1; p[2] = o2; p[3] = o3;
}

// ---------------- transpose + convert: w[K][N] fp32 -> wt[N][K] bf16 ----------------
__global__ __launch_bounds__(256) void transpose_kernel(const float* __restrict__ in,
                                                        u16* __restrict__ out,
                                                        int K, int N) {
    __shared__ float t[32][33];
    int n0 = blockIdx.x * 32, k0 = blockIdx.y * 32;
    int x = threadIdx.x, y = threadIdx.y;
#pragma unroll
    for (int i = 0; i < 4; i++)
        t[y + 8 * i][x] = in[(size_t)(k0 + y + 8 * i) * N + n0 + x];
    __syncthreads();
#pragma unroll
    for (int i = 0; i < 4; i++)
        out[(size_t)(n0 + y + 8 * i) * K + k0 + x] = f2bf(t[x][y + 8 * i]);
}

// ---------------- fused wq|wk|wv transpose into wqkvt[6144][4096] ----------------
__global__ __launch_bounds__(256) void wqkv_trans_kernel(const float* __restrict__ wq,
                                                         const float* __restrict__ wk,
                                                         const float* __restrict__ wv,
                                                         u16* __restrict__ out) {
    __shared__ float t[32][33];
    int n0 = blockIdx.x * 32, k0 = blockIdx.y * 32;
    const float* src; int srcN, nc;
    if (n0 < 4096)      { src = wq; srcN = 4096; nc = n0; }
    else if (n0 < 5120) { src = wk; srcN = 1024; nc = n0 - 4096; }
    else                { src = wv; srcN = 1024; nc = n0 - 5120; }
    int x = threadIdx.x, y = threadIdx.y;
#pragma unroll
    for (int i = 0; i < 4; i++)
        t[y + 8 * i][x] = src[(size_t)(k0 + y + 8 * i) * srcN + nc + x];
    __syncthreads();
#pragma unroll
    for (int i = 0; i < 4; i++)
        out[(size_t)(n0 + y + 8 * i) * 4096 + k0 + x] = f2bf(t[x][y + 8 * i]);
}

// ---------------- bf16 transpose for V: qkv cols [5120..6144) -> vt[b][dcol][seq] ----
__global__ __launch_bounds__(256) void vtrans_kernel(const u16* __restrict__ qkv,
                                                     u16* __restrict__ vt) {
    __shared__ u16 t[32][33];
    int b = blockIdx.z;
    int c0 = blockIdx.x * 32;
    int r0 = blockIdx.y * 32;
    int x = threadIdx.x, y = threadIdx.y;
    const u16* in = qkv + (size_t)(b * SEQ) * QKVN + 5120;
#pragma unroll
    for (int i = 0; i < 4; i++)
        t[y + 8 * i][x] = in[(size_t)(r0 + y + 8 * i) * QKVN + c0 + x];
    __syncthreads();
    u16* out = vt + (size_t)b * 1024 * SEQ;
#pragma unroll
    for (int i = 0; i < 4; i++)
        out[(size_t)(c0 + y + 8 * i) * SEQ + r0 + x] = t[x][y + 8 * i];
}

// ---------------- GEMM (m97 structure + L2 swizzle): C = A * Bt^T ----------------
// 128x128 tile, BK=32, global_load_lds w16. Super-tile 16m x 8n for L2 locality.
template <bool OUT_F32>
__global__ __launch_bounds__(256, 2) void gemm_lds(const u16* __restrict__ A,
                                                   const u16* __restrict__ Bt,
                                                   void* __restrict__ C,
                                                   int M, int N, int K) {
    __shared__ u16 lA[128 * 32];
    __shared__ u16 lB[128 * 32];
    int tid = threadIdx.x, wave = tid >> 6, lane = tid & 63;
    int quad = lane >> 4, l16 = lane & 15;
    // swizzle: 128-block super-tiles (16 m-tiles x 8 n-tiles), n fastest within
    int lb = blockIdx.y * gridDim.x + blockIdx.x;
    int scols = gridDim.x >> 3;
    int s = lb >> 7, r = lb & 127;
    int bn = (s % scols) * 8 + (r & 7);
    int bm = (s / scols) * 16 + (r >> 3);
    int m0 = bm * 128, n0 = bn * 128;
    int wm = (wave >> 1) * 64, wn = (wave & 1) * 64;
    int lrow = lane >> 2, lcol = (lane & 3) * 8;

    const u16* ga = A + (size_t)(m0 + wave * 32 + lrow) * K + lcol;
    const u16* gb = Bt + (size_t)(n0 + wave * 32 + lrow) * K + lcol;
    u16* la = lA + (wave * 32) * 32;
    u16* lb2 = lB + (wave * 32) * 32;

    f32x4 acc[4][4] = {};

    gload16(ga, la);
    gload16(ga + (size_t)16 * K, la + 512);
    gload16(gb, lb2);
    gload16(gb + (size_t)16 * K, lb2 + 512);

    for (int k0 = 0; k0 < K; k0 += 32) {
        __syncthreads();
        bf16x8 af[4], bfr[4];
#pragma unroll
        for (int i = 0; i < 4; i++)
            af[i] = *(const bf16x8*)(lA + (wm + i * 16 + l16) * 32 + quad * 8);
#pragma unroll
        for (int j = 0; j < 4; j++)
            bfr[j] = *(const bf16x8*)(lB + (wn + j * 16 + l16) * 32 + quad * 8);
        if (k0 + 32 < K) {
            __syncthreads();
            gload16(ga + k0 + 32, la);
            gload16(ga + (size_t)16 * K + k0 + 32, la + 512);
            gload16(gb + k0 + 32, lb2);
            gload16(gb + (size_t)16 * K + k0 + 32, lb2 + 512);
        }
#pragma unroll
        for (int i = 0; i < 4; i++)
#pragma unroll
            for (int j = 0; j < 4; j++)
                acc[i][j] = mfma16(af[i], bfr[j], acc[i][j]);
    }

#pragma unroll
    for (int i = 0; i < 4; i++)
#pragma unroll
        for (int j = 0; j < 4; j++) {
            int row = m0 + wm + i * 16 + quad * 4;
            int col = n0 + wn + j * 16 + l16;
            if (OUT_F32) {
                float* Cf = (float*)C;
#pragma unroll
                for (int r2 = 0; r2 < 4; r2++)
                    Cf[(size_t)(row + r2) * N + col] = acc[i][j][r2];
            } else {
                u16* Cb = (u16*)C;
#pragma unroll
                for (int r2 = 0; r2 < 4; r2++)
                    Cb[(size_t)(row + r2) * N + col] = f2bf(acc[i][j][r2]);
            }
        }
}

// ---------------- RoPE on fused qkv buffer ----------------
__global__ __launch_bounds__(256) void rope2_kernel(u16* __restrict__ buf,
                                                    const float* __restrict__ cosb,
                                                    const float* __restrict__ sinb,
                                                    int nheads, int colbase, float scale) {
    int idx = blockIdx.x * 256 + threadIdx.x;
    int p = idx & 63;
    int rest = idx >> 6;
    int h = rest & (nheads - 1);
    int tok = rest / nheads;
    int tseq = tok & (SEQ - 1);
    float c = cosb[tseq * 64 + p], s = sinb[tseq * 64 + p];
    u32* ptr = (u32*)(buf + (size_t)tok * QKVN + colbase + h * DHEAD + 2 * p);
    u32 v = *ptr;
    float xr = bf2f((u16)(v & 0xffff)), xi = bf2f((u16)(v >> 16));
    *ptr = pk_bf2((xr * c - xi * s) * scale, (xr * s + xi * c) * scale);
}

// ---------------- Flash attention v3 (O^T accumulation, exp2 domain) ----------------
// grid (16, 32, 2) = (qtile, head, b), 256 thr = 4 waves, 128 q/block, 64-key tiles.
// S^T = K*Q^T; O^T = V^T*P^T (alpha/l indexed by l16 -> no broadcast shuffles).
#define LDP 72
#define NINF (-__builtin_inff())

__global__ __launch_bounds__(256, 2) void flash3_kernel(const u16* __restrict__ QKV,
                                                        const u16* __restrict__ Vt,
                                                        u16* __restrict__ Z) {
    __shared__ u16 sm[25600];
    u16* lKb = sm;             // [4][64*32]  kk-chunk, [key][dcol32]
    u16* lVb = sm + 8192;      // [2][128*32] kf-chunk, [d][keycol32]
    u16* lPb = sm + 16384;     // [4][32*LDP] per-wave P [q][key]
    int tid = threadIdx.x, wave = tid >> 6, lane = tid & 63;
    int quad = lane >> 4, l16 = lane & 15;
    int qt = 15 - (int)blockIdx.x;
    int h = blockIdx.y, b = blockIdx.z;
    int kvh = h >> 2;
    int Q0 = qt * 128;
    int qw = Q0 + wave * 32;
    int lrow = lane >> 2, lcol = (lane & 3) * 8;

    bf16x8 qf[2][4];
#pragma unroll
    for (int nt = 0; nt < 2; nt++) {
        const u16* qp = QKV + (size_t)(b * SEQ + qw + nt * 16 + l16) * QKVN + h * DHEAD;
#pragma unroll
        for (int kk = 0; kk < 4; kk++)
            qf[nt][kk] = *(const bf16x8*)(qp + kk * 32 + quad * 8);
    }

    f32x4 o[8][2] = {};  // O^T[dtile][qtile]: rows d, cols q(l16)
    float mrun[2] = {NINF, NINF};
    float lrun[2] = {0.f, 0.f};

    const u16* gk = QKV + (size_t)(b * SEQ + lrow) * QKVN + DMODEL + kvh * DHEAD + wave * 32 + lcol;
    u16* lk = lKb + wave * 2048;
    int kf_w = wave >> 1, dh_w = (wave & 1) * 64;
    const u16* gv = Vt + ((size_t)(b * NKV + kvh) * DHEAD + dh_w + lrow) * SEQ + kf_w * 32 + lcol;
    u16* lv = lVb + kf_w * 4096 + dh_w * 32;
    u16* lp = lPb + wave * (32 * LDP);

    int nkt = 2 * qt + 2;
    for (int kt = 0; kt < nkt; kt++) {
        int key0 = kt * 64;
        if (kt) __syncthreads();
#pragma unroll
        for (int g = 0; g < 4; g++)
            gload16(gk + (size_t)(key0 + g * 16) * QKVN, lk + g * 512);
#pragma unroll
        for (int g = 0; g < 4; g++)
            gload16(gv + (size_t)(g * 16) * SEQ + key0, lv + g * 512);
        __syncthreads();

        if (key0 > qw + 31) continue;

        // S^T: rows key (4 mt tiles), cols q (2 nt tiles)
        f32x4 st[4][2] = {};
#pragma unroll
        for (int kk = 0; kk < 4; kk++) {
            bf16x8 kfr[4];
#pragma unroll
            for (int mt = 0; mt < 4; mt++)
                kfr[mt] = *(const bf16x8*)(lKb + kk * 2048 + (mt * 16 + l16) * 32 + quad * 8);
#pragma unroll
            for (int mt = 0; mt < 4; mt++)
#pragma unroll
                for (int nt = 0; nt < 2; nt++)
                    st[mt][nt] = mfma16(kfr[mt], qf[nt][kk], st[mt][nt]);
        }
        // causal mask: per-subtile, wave-uniform branch
#pragma unroll
        for (int mt = 0; mt < 4; mt++)
#pragma unroll
            for (int nt = 0; nt < 2; nt++) {
                int kmin = key0 + mt * 16, qmin = qw + nt * 16;
                if (kmin + 15 <= qmin) continue;           // fully unmasked
                if (kmin > qmin + 15) {                    // fully masked
                    st[mt][nt] = (f32x4){NINF, NINF, NINF, NINF};
                } else {
#pragma unroll
                    for (int r = 0; r < 4; r++)
                        if (kmin + quad * 4 + r > qmin + l16) st[mt][nt][r] = NINF;
                }
            }
        float alpha[2];
#pragma unroll
        for (int nt = 0; nt < 2; nt++) {
            float vmax = NINF;
#pragma unroll
            for (int mt = 0; mt < 4; mt++)
#pragma unroll
                for (int r = 0; r < 4; r++) vmax = fmaxf(vmax, st[mt][nt][r]);
            vmax = fmaxf(vmax, __shfl_xor(vmax, 16));
            vmax = fmaxf(vmax, __shfl_xor(vmax, 32));
            float mnew = fmaxf(mrun[nt], vmax);
            alpha[nt] = __builtin_amdgcn_exp2f(mrun[nt] - mnew);
            mrun[nt] = mnew;
            float rsum = 0.f;
#pragma unroll
            for (int mt = 0; mt < 4; mt++)
#pragma unroll
                for (int r = 0; r < 4; r++) {
                    float p = __builtin_amdgcn_exp2f(st[mt][nt][r] - mnew);
                    st[mt][nt][r] = p;
                    rsum += p;
                }
            rsum += __shfl_xor(rsum, 16);
            rsum += __shfl_xor(rsum, 32);
            lrun[nt] = lrun[nt] * alpha[nt] + rsum;
#pragma unroll
            for (int mt = 0; mt < 4; mt++) {
                uint2 pk;
                pk.x = pk_bf2(st[mt][nt][0], st[mt][nt][1]);
                pk.y = pk_bf2(st[mt][nt][2], st[mt][nt][3]);
                *(uint2*)(lp + (nt * 16 + l16) * LDP + mt * 16 + quad * 4) = pk;
            }
        }
        // rescale O^T (alpha per l16 = per q, exact, no shuffle)
#pragma unroll
        for (int dt = 0; dt < 8; dt++)
#pragma unroll
            for (int nt = 0; nt < 2; nt++)
#pragma unroll
                for (int r = 0; r < 4; r++) o[dt][nt][r] *= alpha[nt];
        // PV: O^T[d][q] += V^T[d][key] * P^T[key][q]
#pragma unroll
        for (int kfi = 0; kfi < 2; kfi++) {
            bf16x8 pf0 = *(const bf16x8*)(lp + l16 * LDP + kfi * 32 + quad * 8);
            bf16x8 pf1 = *(const bf16x8*)(lp + (16 + l16) * LDP + kfi * 32 + quad * 8);
#pragma unroll
            for (int dt = 0; dt < 8; dt++) {
                bf16x8 vfr = *(const bf16x8*)(lVb + kfi * 4096 + (dt * 16 + l16) * 32 + quad * 8);
                o[dt][0] = mfma16(vfr, pf0, o[dt][0]);
                o[dt][1] = mfma16(vfr, pf1, o[dt][1]);
            }
        }
    }

    // epilogue: O^T -> LDS transpose -> coalesced Z stores
    __syncthreads();
    u16* ebuf = sm + wave * 4352;  // [32 q][136]
    float linv[2];
    linv[0] = 1.0f / lrun[0];
    linv[1] = 1.0f / lrun[1];
#pragma unroll
    for (int dt = 0; dt < 8; dt++)
#pragma unroll
        for (int nt = 0; nt < 2; nt++) {
            uint2 pk;
            pk.x = pk_bf2(o[dt][nt][0] * linv[nt], o[dt][nt][1] * linv[nt]);
            pk.y = pk_bf2(o[dt][nt][2] * linv[nt], o[dt][nt][3] * linv[nt]);
            *(uint2*)(ebuf + (nt * 16 + l16) * 136 + dt * 16 + quad * 4) = pk;
        }
    int eq = lane >> 1, ed = (lane & 1) * 8;
    u16* zrow = Z + (size_t)(b * SEQ + qw + eq) * DMODEL + h * DHEAD + ed;
#pragma unroll
    for (int half = 0; half < 8; half++) {
        u16x8 v = *(const u16x8*)(ebuf + eq * 136 + half * 16 + ed);
        *(u16x8*)(zrow + half * 16) = v;
    }
}

extern "C" void kernel_launch(void* const* d_in, const int* in_sizes, int n_in,
                              void* d_out, int out_size, void* d_ws, size_t ws_size,
                              hipStream_t stream) {
    const float* x    = (const float*)d_in[0];
    const float* fcos = (const float*)d_in[1];
    const float* fsin = (const float*)d_in[2];
    const float* wq   = (const float*)d_in[3];
    const float* wk   = (const float*)d_in[4];
    const float* wv   = (const float*)d_in[5];
    const float* wo   = (const float*)d_in[6];
    float* out = (float*)d_out;
    char* ws = (char*)d_ws;

    const size_t MiB = 1024ull * 1024ull;
    u16* xb    = (u16*)(ws);              // 32MiB; reused as zb
    u16* zb    = xb;
    u16* wqkvt = (u16*)(ws + 32 * MiB);   // 48MiB [6144][4096]
    u16* wot   = (u16*)(ws + 80 * MiB);   // 32MiB [4096][4096]
    u16* qkv   = (u16*)(ws + 112 * MiB);  // 48MiB [4096][6144]
    u16* vtb   = (u16*)(ws + 160 * MiB);  // 8MiB  [2][1024][2048]

    f2bf_kernel<<<16384, 256, 0, stream>>>(x, xb, TOKENS * DMODEL);
    dim3 tb(32, 8);
    wqkv_trans_kernel<<<dim3(192, 128), tb, 0, stream>>>(wq, wk, wv, wqkvt);
    transpose_kernel<<<dim3(128, 128), tb, 0, stream>>>(wo, wot, 4096, 4096);

    gemm_lds<false><<<dim3(48, 32), 256, 0, stream>>>(xb, wqkvt, qkv, 4096, QKVN, 4096);

    // Q pre-scale = (1/sqrt(128)) * log2(e)  (exp2-domain softmax)
    rope2_kernel<<<32768, 256, 0, stream>>>(qkv, fcos, fsin, NHEAD, 0, 0.12751744416163924f);
    rope2_kernel<<<8192, 256, 0, stream>>>(qkv, fcos, fsin, NKV, DMODEL, 1.0f);

    vtrans_kernel<<<dim3(32, 64, 2), tb, 0, stream>>>(qkv, vtb);

    flash3_kernel<<<dim3(16, 32, 2), 256, 0, stream>>>(qkv, vtb, zb);

    gemm_lds<true><<<dim3(32, 32), 256, 0, stream>>>(zb, wot, out, 4096, 4096, 4096);
}